// Round 1
// baseline (283.647 us; speedup 1.0000x reference)
//
#include <hip/hip_runtime.h>
#include <cstdint>
#include <cstddef>

// ---- problem constants ----
#define SEQ 2048
#define DMODEL 1024
#define NH 16
#define HD 64
#define NB 20

typedef _Float16 half8 __attribute__((ext_vector_type(8)));
typedef _Float16 half4 __attribute__((ext_vector_type(4)));
typedef float f32x4 __attribute__((ext_vector_type(4)));
typedef float f4 __attribute__((ext_vector_type(4)));
typedef int i32x4 __attribute__((ext_vector_type(4)));

// ws layout (halves): Qh [2][2048][1024] | Kimg [2][64][32768] | Vimg [2][64][32768]
#define QH_ELEMS (2 * SEQ * DMODEL)          // 4,194,304
#define IMG_ELEMS 32768                      // one (b,ktile) image: 32 rows x 1024 cols (halves)
#define NKT 64                               // k-tiles per batch (KB=32)

// K image: row-major [32][1024], elem swizzle: e = (r*1024 + c) ^ ((r&7)<<3)   (16B granule XOR)
// V image: transposed [1024 d][32 kk],  elem swizzle: e = (d*32 + kk) ^ ((d&7)<<2) (8B granule XOR)

__device__ __forceinline__ void gll16(const _Float16* g, _Float16* l) {
  __builtin_amdgcn_global_load_lds(
      (const __attribute__((address_space(1))) unsigned int*)g,
      (__attribute__((address_space(3))) unsigned int*)l, 16, 0, 0);
}

// ---------------- prepass: fp32 -> fp16, tile + swizzle K and V ----------------
__global__ __launch_bounds__(256) void pa_prep(
    const float* __restrict__ v, const float* __restrict__ k, const float* __restrict__ q,
    _Float16* __restrict__ Qh, _Float16* __restrict__ Kimg, _Float16* __restrict__ Vimg) {
  int bid = blockIdx.x, tid = threadIdx.x;
  if (bid < 2048) {
    // Q flat convert, 8 elems / thread
    size_t e0 = ((size_t)bid * 256 + tid) * 8;
    f4 a = *(const f4*)&q[e0];
    f4 b = *(const f4*)&q[e0 + 4];
    half8 o = {(_Float16)a[0], (_Float16)a[1], (_Float16)a[2], (_Float16)a[3],
               (_Float16)b[0], (_Float16)b[1], (_Float16)b[2], (_Float16)b[3]};
    *(half8*)&Qh[e0] = o;
  } else if (bid < 4096) {
    // K tiler: 16 blocks per image
    int b2 = bid - 2048;
    int img = b2 >> 4;                 // 0..127  (b*64 + kt)
    int bb = img >> 6, kt = img & 63;
    int tix = ((b2 & 15) << 8) | tid;  // 0..4095
    int r = tix >> 7;                  // 0..31
    int c0 = (tix & 127) << 3;         // 0..1016
    const float* src = &k[((size_t)(bb * SEQ) + kt * 32 + r) * DMODEL + c0];
    f4 a = *(const f4*)src;
    f4 b = *(const f4*)(src + 4);
    half8 o = {(_Float16)a[0], (_Float16)a[1], (_Float16)a[2], (_Float16)a[3],
               (_Float16)b[0], (_Float16)b[1], (_Float16)b[2], (_Float16)b[3]};
    int e = ((r << 10) | c0) ^ ((r & 7) << 3);
    *(half8*)&Kimg[(size_t)img * IMG_ELEMS + e] = o;
  } else {
    // V tiler (transpose): 8 blocks per image
    int b3 = bid - 4096;
    int img = b3 >> 3;                 // 0..127
    int bb = img >> 6, kt = img & 63;
    int tix = ((b3 & 7) << 8) | tid;   // 0..2047
    int kr0 = (tix >> 8) << 2;         // 0,4,...,28
    int d0 = (tix & 255) << 2;         // 0..1020 step 4
    const float* src = &v[((size_t)(bb * SEQ) + kt * 32 + kr0) * DMODEL + d0];
    f4 m0 = *(const f4*)(src);
    f4 m1 = *(const f4*)(src + DMODEL);
    f4 m2 = *(const f4*)(src + 2 * DMODEL);
    f4 m3 = *(const f4*)(src + 3 * DMODEL);
#pragma unroll
    for (int i2 = 0; i2 < 4; ++i2) {
      int d = d0 + i2;
      half4 o = {(_Float16)m0[i2], (_Float16)m1[i2], (_Float16)m2[i2], (_Float16)m3[i2]};
      int e = ((d << 5) | kr0) ^ ((d & 7) << 2);
      *(half4*)&Vimg[(size_t)img * IMG_ELEMS + e] = o;
    }
  }
}

// ---------------- main kernel ----------------
// grid 256 x 1024 threads. wave w = head w. QB=32 (2 q-subtiles), KB=32, ksplit=2.
// block id -> xcd-grouped: grp=(bid&7)>>1 selects (b,khalf); 2 XCDs per group share a 4MB K/V stream.
__global__ __launch_bounds__(1024) void pa_main(
    const _Float16* __restrict__ Qh, const _Float16* __restrict__ Kimg,
    const _Float16* __restrict__ Vimg, const int* __restrict__ diff,
    const int* __restrict__ mask, const float* __restrict__ relbias,
    float* __restrict__ out) {
  extern __shared__ char smem_raw[];
  _Float16* ldsK = (_Float16*)smem_raw;                 // 64 KB
  _Float16* ldsV = ldsK + IMG_ELEMS;                    // 64 KB
  float* rb = (float*)(ldsV + IMG_ELEMS);               // [16][20] transposed rel_bias

  const int tid = threadIdx.x;
  const int lane = tid & 63, wid = tid >> 6;            // wid = head
  const int l16 = lane & 15, g4 = lane >> 4;
  const int bid = blockIdx.x;
  const int grp = (bid & 7) >> 1;                       // 0..3 = b*2 + khalf
  const int b = grp >> 1, ksp = grp & 1;
  const int qblk = ((bid & 1) << 5) | (bid >> 3);       // 0..63
  const int qbase = qblk * 32;
  const int h = wid;

  if (tid < NB * NH) {
    int hh = tid / NB, dd = tid - hh * NB;
    rb[hh * NB + dd] = relbias[dd * NH + hh];           // rb[h][bucket]
  }

  // Q fragments (resident): qf[qsub][dhalf], B-operand layout: col q = l16, k = g4*8+j
  half8 qf[2][2];
#pragma unroll
  for (int qs = 0; qs < 2; ++qs)
#pragma unroll
    for (int dh = 0; dh < 2; ++dh)
      qf[qs][dh] = *(const half8*)&Qh[((size_t)(b * SEQ) + qbase + qs * 16 + l16) * DMODEL +
                                      h * 64 + dh * 32 + g4 * 8];

  const f32x4 zf = {0.f, 0.f, 0.f, 0.f};
  f32x4 acc[2][4];
#pragma unroll
  for (int qs = 0; qs < 2; ++qs)
#pragma unroll
    for (int dt = 0; dt < 4; ++dt) acc[qs][dt] = zf;

  const _Float16* Kb = Kimg + ((size_t)(b * NKT) + ksp * 32) * IMG_ELEMS;
  const _Float16* Vb = Vimg + ((size_t)(b * NKT) + ksp * 32) * IMG_ELEMS;

  for (int t = 0; t < 32; ++t) {
    // stage 64KB K + 64KB V images (pre-swizzled in ws -> linear copy)
    const _Float16* kg = Kb + (size_t)t * IMG_ELEMS + wid * 2048 + lane * 8;
    const _Float16* vg = Vb + (size_t)t * IMG_ELEMS + wid * 2048 + lane * 8;
#pragma unroll
    for (int i = 0; i < 4; ++i) {
      gll16(kg + i * 512, &ldsK[(wid * 4 + i) * 512]);
      gll16(vg + i * 512, &ldsV[(wid * 4 + i) * 512]);
    }
    __syncthreads();   // drains vmcnt; LDS images ready

    const int kb2 = ksp * 1024 + t * 32;
#pragma unroll
    for (int k2 = 0; k2 < 2; ++k2) {
      // K fragments: A layout row kk = l16 (+16*k2), k = d = g4*8+j
      half8 kf0, kf1;
      {
        int r = k2 * 16 + l16;
        int c = h * 64 + g4 * 8;
        kf0 = *(const half8*)&ldsK[((r << 10) | c) ^ ((r & 7) << 3)];
        kf1 = *(const half8*)&ldsK[((r << 10) | (c + 32)) ^ ((r & 7) << 3)];
      }
      // S^T = K * Q^T  (per q-subtile), fp32 accum
      f32x4 sa[2];
#pragma unroll
      for (int qs = 0; qs < 2; ++qs) {
        sa[qs] = __builtin_amdgcn_mfma_f32_16x16x32_f16(kf0, qf[qs][0], zf, 0, 0, 0);
        sa[qs] = __builtin_amdgcn_mfma_f32_16x16x32_f16(kf1, qf[qs][1], sa[qs], 0, 0, 0);
      }
      // V fragments: B layout col d = l16 (+16*dt), k = kk = g4*4+j (+16*k2)
      half4 vf[4];
#pragma unroll
      for (int dt = 0; dt < 4; ++dt) {
        int d = h * 64 + dt * 16 + l16;
        int kk = k2 * 16 + g4 * 4;
        vf[dt] = *(const half4*)&ldsV[((d << 5) | kk) ^ ((d & 7) << 2)];
      }
      // bias gather + silu + mask + cvt to fp16 P (A-frag layout == S^T D-layout)
      half4 pf[2];
#pragma unroll
      for (int qs = 0; qs < 2; ++qs) {
        size_t rowoff = ((size_t)(b * SEQ) + qbase + qs * 16 + l16) * SEQ +
                        kb2 + k2 * 16 + g4 * 4;
        i32x4 dv = *(const i32x4*)&diff[rowoff];
        i32x4 mv = *(const i32x4*)&mask[rowoff];
#pragma unroll
        for (int r = 0; r < 4; ++r) {
          float x = sa[qs][r] * 0.125f + rb[h * NB + dv[r]];
          float sg = 1.0f / (1.0f + __expf(-x));
          float y = mv[r] ? x * sg : 0.0f;
          pf[qs][r] = (_Float16)y;
        }
      }
      // O += P * V
#pragma unroll
      for (int qs = 0; qs < 2; ++qs)
#pragma unroll
        for (int dt = 0; dt < 4; ++dt)
          acc[qs][dt] = __builtin_amdgcn_mfma_f32_16x16x16f16(pf[qs], vf[dt], acc[qs][dt], 0, 0, 0);
    }
    __syncthreads();   // protect LDS before next tile's staging
  }

  // epilogue: ksplit=2 partial sums -> atomicAdd into zeroed out
#pragma unroll
  for (int qs = 0; qs < 2; ++qs)
#pragma unroll
    for (int dt = 0; dt < 4; ++dt)
#pragma unroll
      for (int r = 0; r < 4; ++r) {
        int qrow = qbase + qs * 16 + g4 * 4 + r;
        int d = h * 64 + dt * 16 + l16;
        atomicAdd(&out[((size_t)(b * SEQ) + qrow) * DMODEL + d], acc[qs][dt][r]);
      }
}

extern "C" void kernel_launch(void* const* d_in, const int* in_sizes, int n_in,
                              void* d_out, int out_size, void* d_ws, size_t ws_size,
                              hipStream_t stream) {
  const float* v = (const float*)d_in[0];
  const float* k = (const float*)d_in[1];
  const float* q = (const float*)d_in[2];
  const int* mask = (const int*)d_in[3];      // jnp.bool_ assumed marshalled as int32
  const int* diff = (const int*)d_in[4];
  const float* relbias = (const float*)d_in[5];
  float* out = (float*)d_out;

  _Float16* Qh = (_Float16*)d_ws;
  _Float16* Kimg = Qh + QH_ELEMS;
  _Float16* Vimg = Kimg + (size_t)2 * NKT * IMG_ELEMS;
  // ws required: 3 * 4,194,304 halves = 25,165,824 B
  if (ws_size < (size_t)25165824) return;

  hipMemsetAsync(d_out, 0, (size_t)out_size * sizeof(float), stream);
  pa_prep<<<5120, 256, 0, stream>>>(v, k, q, Qh, Kimg, Vimg);
  size_t lds_bytes = (size_t)2 * IMG_ELEMS * sizeof(_Float16) + NB * NH * sizeof(float);
  pa_main<<<256, 1024, lds_bytes, stream>>>(Qh, Kimg, Vimg, diff, mask, relbias, out);
}

// Round 2
// 108.251 us; speedup vs baseline: 2.6203x; 2.6203x over previous
//
#include <hip/hip_runtime.h>
#include <cstdint>
#include <cstddef>

// ---- problem constants ----
#define SEQ 2048
#define DM 1024
#define NH 16
#define NB 20

typedef _Float16 half8 __attribute__((ext_vector_type(8)));
typedef _Float16 half4 __attribute__((ext_vector_type(4)));
typedef float f32x4 __attribute__((ext_vector_type(4)));
typedef int i32x4 __attribute__((ext_vector_type(4)));
typedef unsigned int u32;
typedef unsigned int u32x2 __attribute__((ext_vector_type(2)));

// ws layout (25,165,824 B total):
//  KF [2][16][64][2048] halves : per (b,h,kt): [k2][dh][lane][8]   (QK^T A-frags)
//  VF [2][16][64][2048] halves : per (b,h,kt): [k2][dtp][lane][8]  (PV B-frags)
//  PB [2][64][65536] bytes     : per (b,qblk): [kt][qs][lane][k2][4] packed diff|mask
#define KF_HALVES 4194304
#define VF_HALVES 4194304

// =================== prepass: fragment-order everything ===================
__global__ __launch_bounds__(256) void pa_prep(
    const float* __restrict__ v, const float* __restrict__ k,
    const int* __restrict__ diff, const int* __restrict__ mask,
    _Float16* __restrict__ KF, _Float16* __restrict__ VF,
    unsigned char* __restrict__ PB) {
  const int bid = blockIdx.x, tid = threadIdx.x;
  if (bid < 2048) {
    // ---- K fragment tiler: 16 blocks per (b,kt) image ----
    int img = bid >> 4;                    // 0..127 = b*64+kt
    int bb = img >> 6, kt = img & 63;
    int tix = ((bid & 15) << 8) | tid;     // 0..4095
    int r = tix >> 7;                      // row in tile 0..31 (= k2*16+l16)
    int c0 = (tix & 127) << 3;             // col 0..1016
    const float* src = k + ((size_t)(bb * SEQ + kt * 32 + r)) * DM + c0;
    f32x4 a = *(const f32x4*)src;
    f32x4 c = *(const f32x4*)(src + 4);
    half8 o = {(_Float16)a[0], (_Float16)a[1], (_Float16)a[2], (_Float16)a[3],
               (_Float16)c[0], (_Float16)c[1], (_Float16)c[2], (_Float16)c[3]};
    int h = c0 >> 6, dh = (c0 >> 5) & 1, g4 = (c0 >> 3) & 3;
    int k2 = r >> 4, l16 = r & 15;
    int lane = g4 * 16 + l16;
    size_t off = ((size_t)((bb * 16 + h) * 64 + kt)) * 2048 + (k2 * 2 + dh) * 512 + lane * 8;
    *(half8*)(KF + off) = o;
  } else if (bid < 3072) {
    // ---- V fragment tiler (transpose): 8 blocks per (b,kt) image ----
    int b3 = bid - 2048;
    int img = b3 >> 3;                     // 0..127
    int bb = img >> 6, kt = img & 63;
    int tix = ((b3 & 7) << 8) | tid;       // 0..2047
    int kq = tix >> 8;                     // 0..7
    int k2 = kq >> 2, g4 = kq & 3;
    int d0 = (tix & 255) << 2;             // 0..1020
    const float* src = v + ((size_t)(bb * SEQ + kt * 32 + k2 * 16 + g4 * 4)) * DM + d0;
    f32x4 m0 = *(const f32x4*)(src);
    f32x4 m1 = *(const f32x4*)(src + DM);
    f32x4 m2 = *(const f32x4*)(src + 2 * DM);
    f32x4 m3 = *(const f32x4*)(src + 3 * DM);
#pragma unroll
    for (int i = 0; i < 4; ++i) {
      int d = d0 + i;
      int l16 = d & 15, dt = (d >> 4) & 3, dtp = dt >> 1, w = dt & 1, h = d >> 6;
      int lane = g4 * 16 + l16;
      half4 o = {(_Float16)m0[i], (_Float16)m1[i], (_Float16)m2[i], (_Float16)m3[i]};
      size_t off = ((size_t)((bb * 16 + h) * 64 + kt)) * 2048 + (k2 * 2 + dtp) * 512 + lane * 8 + w * 4;
      *(half4*)(VF + off) = o;
    }
  } else {
    // ---- packed diff|mask byte tiler: 32 blocks per (b,qblk) job ----
    int b4 = bid - 3072;                   // 0..4095
    int job = b4 >> 5;                     // 0..127 = b*64+qblk
    int bb = job >> 6, qblk = job & 63;
    int tix = ((b4 & 31) << 8) | tid;      // 0..8191
    int kt = tix >> 7;
    int rem = tix & 127;
    int g4 = rem & 3, l16 = (rem >> 2) & 15, qs = rem >> 6;
    int lane = g4 * 16 + l16;
    int qrow = qblk * 32 + qs * 16 + l16;
    size_t rowbase = ((size_t)(bb * SEQ + qrow)) * SEQ;
    u32x2 wds;
#pragma unroll
    for (int k2 = 0; k2 < 2; ++k2) {
      int kk = kt * 32 + k2 * 16 + g4 * 4;
      i32x4 dv = *(const i32x4*)(diff + rowbase + kk);
      i32x4 mv = *(const i32x4*)(mask + rowbase + kk);
      u32 wd = 0;
#pragma unroll
      for (int r = 0; r < 4; ++r) {
        u32 byte = mv[r] ? (u32)dv[r] : 20u;  // bucket 20 = masked sentinel
        wd |= byte << (8 * r);
      }
      wds[k2] = wd;
    }
    size_t off = ((size_t)job) * 65536 + (size_t)(kt * 2 + qs) * 512 + lane * 8;
    *(u32x2*)(PB + off) = wds;
  }
}

// =================== main: barrier-free per-wave streaming ===================
// 1024 blocks x 256 thr (4 waves). g=bid&7 -> (b,ksp,hh) pinned per XCD (L2 fit: 1MB KF+1MB VF+2MB PB).
__global__ __launch_bounds__(256, 4) void pa_main(
    const _Float16* __restrict__ KF, const _Float16* __restrict__ VF,
    const unsigned char* __restrict__ PB, const float* __restrict__ q,
    const float* __restrict__ relbias, float* __restrict__ out) {
  const int tid = threadIdx.x, lane = tid & 63, wid = tid >> 6;
  const int l16 = lane & 15, g4 = lane >> 4;
  const int bid = blockIdx.x;
  const int g = bid & 7;
  const int b = g >> 2, ksp = (g >> 1) & 1, hh = g & 1;
  const int rid = bid >> 3;
  const int qblk = rid & 63, hq = rid >> 6;
  const int h = hh * 8 + hq * 4 + wid;
  const int qbase = qblk * 32;

  // rel_bias for this head lives in lanes 0..20 (lane 20 = masked sentinel)
  float rbv = -30000.f;
  if (lane < NB) rbv = relbias[lane * NH + h];
  const int rbi = __float_as_int(rbv);

  // Q fragments: fp32 -> fp16 in-register (B-operand: col q=l16, k=d=g4*8+j)
  half8 qf[2][2];
#pragma unroll
  for (int qs = 0; qs < 2; ++qs)
#pragma unroll
    for (int dh = 0; dh < 2; ++dh) {
      const float* s = q + ((size_t)(b * SEQ + qbase + qs * 16 + l16)) * DM + h * 64 + dh * 32 + g4 * 8;
      f32x4 a = *(const f32x4*)s;
      f32x4 c = *(const f32x4*)(s + 4);
      qf[qs][dh] = {(_Float16)a[0], (_Float16)a[1], (_Float16)a[2], (_Float16)a[3],
                    (_Float16)c[0], (_Float16)c[1], (_Float16)c[2], (_Float16)c[3]};
    }

  const f32x4 zf = {0.f, 0.f, 0.f, 0.f};
  f32x4 acc[2][4];
#pragma unroll
  for (int qs = 0; qs < 2; ++qs)
#pragma unroll
    for (int dt = 0; dt < 4; ++dt) acc[qs][dt] = zf;

  const _Float16* kfb = KF + ((size_t)((b * 16 + h) * 64 + ksp * 32)) * 2048 + lane * 8;
  const _Float16* vfb = VF + ((size_t)((b * 16 + h) * 64 + ksp * 32)) * 2048 + lane * 8;
  const unsigned char* pbb = PB + ((size_t)(b * 64 + qblk)) * 65536 + (size_t)(ksp * 32) * 1024 + lane * 8;

  for (int t = 0; t < 32; ++t) {
    half8 kf[2][2], vv[2][2];
#pragma unroll
    for (int k2 = 0; k2 < 2; ++k2)
#pragma unroll
      for (int j = 0; j < 2; ++j) {
        kf[k2][j] = *(const half8*)(kfb + (k2 * 2 + j) * 512);
        vv[k2][j] = *(const half8*)(vfb + (k2 * 2 + j) * 512);
      }
    u32x2 pbw[2];
    pbw[0] = *(const u32x2*)(pbb);
    pbw[1] = *(const u32x2*)(pbb + 512);

#pragma unroll
    for (int k2 = 0; k2 < 2; ++k2) {
      // S^T = K * Q^T  (D: q=l16, kk=g4*4+r == PV A-frag layout, zero-shuffle)
      f32x4 sa[2];
#pragma unroll
      for (int qs = 0; qs < 2; ++qs) {
        sa[qs] = __builtin_amdgcn_mfma_f32_16x16x32_f16(kf[k2][0], qf[qs][0], zf, 0, 0, 0);
        sa[qs] = __builtin_amdgcn_mfma_f32_16x16x32_f16(kf[k2][1], qf[qs][1], sa[qs], 0, 0, 0);
      }
      // bias gather (ds_bpermute) + silu; masked -> bias=-3e4 -> silu==0
      half4 pf[2];
#pragma unroll
      for (int qs = 0; qs < 2; ++qs) {
        u32 u = pbw[qs][k2];
#pragma unroll
        for (int r = 0; r < 4; ++r) {
          int idx = (int)(((u >> (8 * r)) & 0xffu) << 2);
          float bias = __int_as_float(__builtin_amdgcn_ds_bpermute(idx, rbi));
          float x = fmaf(sa[qs][r], 0.125f, bias);
          float e = __expf(-x);
          float y = x * __builtin_amdgcn_rcpf(1.0f + e);
          pf[qs][r] = (_Float16)y;
        }
      }
      half4 vf0 = __builtin_shufflevector(vv[k2][0], vv[k2][0], 0, 1, 2, 3);
      half4 vf1 = __builtin_shufflevector(vv[k2][0], vv[k2][0], 4, 5, 6, 7);
      half4 vf2 = __builtin_shufflevector(vv[k2][1], vv[k2][1], 0, 1, 2, 3);
      half4 vf3 = __builtin_shufflevector(vv[k2][1], vv[k2][1], 4, 5, 6, 7);
#pragma unroll
      for (int qs = 0; qs < 2; ++qs) {
        acc[qs][0] = __builtin_amdgcn_mfma_f32_16x16x16f16(pf[qs], vf0, acc[qs][0], 0, 0, 0);
        acc[qs][1] = __builtin_amdgcn_mfma_f32_16x16x16f16(pf[qs], vf1, acc[qs][1], 0, 0, 0);
        acc[qs][2] = __builtin_amdgcn_mfma_f32_16x16x16f16(pf[qs], vf2, acc[qs][2], 0, 0, 0);
        acc[qs][3] = __builtin_amdgcn_mfma_f32_16x16x16f16(pf[qs], vf3, acc[qs][3], 0, 0, 0);
      }
    }
    kfb += 2048; vfb += 2048; pbb += 1024;
  }

  // epilogue: ksplit=2 partials -> atomicAdd into zeroed out
#pragma unroll
  for (int qs = 0; qs < 2; ++qs)
#pragma unroll
    for (int dt = 0; dt < 4; ++dt)
#pragma unroll
      for (int r = 0; r < 4; ++r) {
        int qrow = qbase + qs * 16 + g4 * 4 + r;
        int d = h * 64 + dt * 16 + l16;
        atomicAdd(&out[((size_t)(b * SEQ) + qrow) * DM + d], acc[qs][dt][r]);
      }
}

extern "C" void kernel_launch(void* const* d_in, const int* in_sizes, int n_in,
                              void* d_out, int out_size, void* d_ws, size_t ws_size,
                              hipStream_t stream) {
  const float* v = (const float*)d_in[0];
  const float* k = (const float*)d_in[1];
  const float* q = (const float*)d_in[2];
  const int* mask = (const int*)d_in[3];
  const int* diff = (const int*)d_in[4];
  const float* relbias = (const float*)d_in[5];
  float* out = (float*)d_out;

  _Float16* KF = (_Float16*)d_ws;
  _Float16* VF = KF + KF_HALVES;
  unsigned char* PB = (unsigned char*)(VF + VF_HALVES);
  if (ws_size < (size_t)25165824) return;

  hipMemsetAsync(d_out, 0, (size_t)out_size * sizeof(float), stream);
  pa_prep<<<7168, 256, 0, stream>>>(v, k, diff, mask, KF, VF, PB);
  pa_main<<<1024, 256, 0, stream>>>(KF, VF, PB, q, relbias, out);
}

// Round 4
// 105.810 us; speedup vs baseline: 2.6807x; 1.0231x over previous
//
#include <hip/hip_runtime.h>
#include <hip/hip_fp16.h>
#include <cstdint>
#include <cstddef>

// ---- problem constants ----
#define SEQ 2048
#define DM 1024
#define NH 16
#define NB 20

typedef _Float16 half8 __attribute__((ext_vector_type(8)));
typedef _Float16 half4 __attribute__((ext_vector_type(4)));
typedef _Float16 h2v __attribute__((ext_vector_type(2)));
typedef float f32x4 __attribute__((ext_vector_type(4)));
typedef int i32x4 __attribute__((ext_vector_type(4)));
typedef unsigned int u32;
typedef unsigned int u32x2 __attribute__((ext_vector_type(2)));

// ws layout (25,165,824 B total):
//  KF [2][16][64][2048] halves : per (b,h,kt): [k2][dh][lane][8]   (QK^T A-frags)
//  VF [2][16][64][2048] halves : per (b,h,kt): [k2][dtp][lane][8]  (PV B-frags)
//  PB [2][64][65536] bytes     : per (b,qblk): [kt][lane][qs][k2][4] bucket*4|sentinel80
#define KF_HALVES 4194304
#define VF_HALVES 4194304

// =================== prepass: fragment-order everything ===================
__global__ __launch_bounds__(256) void pa_prep(
    const float* __restrict__ v, const float* __restrict__ k,
    const int* __restrict__ diff, const int* __restrict__ mask,
    _Float16* __restrict__ KF, _Float16* __restrict__ VF,
    unsigned char* __restrict__ PB) {
  const int bid = blockIdx.x, tid = threadIdx.x;
  if (bid < 2048) {
    // ---- K fragment tiler: 16 blocks per (b,kt) image ----
    int img = bid >> 4;                    // 0..127 = b*64+kt
    int bb = img >> 6, kt = img & 63;
    int tix = ((bid & 15) << 8) | tid;     // 0..4095
    int r = tix >> 7;                      // row in tile 0..31 (= k2*16+l16)
    int c0 = (tix & 127) << 3;             // col 0..1016
    const float* src = k + ((size_t)(bb * SEQ + kt * 32 + r)) * DM + c0;
    f32x4 a = *(const f32x4*)src;
    f32x4 c = *(const f32x4*)(src + 4);
    half8 o = {(_Float16)a[0], (_Float16)a[1], (_Float16)a[2], (_Float16)a[3],
               (_Float16)c[0], (_Float16)c[1], (_Float16)c[2], (_Float16)c[3]};
    int h = c0 >> 6, dh = (c0 >> 5) & 1, g4 = (c0 >> 3) & 3;
    int k2 = r >> 4, l16 = r & 15;
    int lane = g4 * 16 + l16;
    size_t off = ((size_t)((bb * 16 + h) * 64 + kt)) * 2048 + (k2 * 2 + dh) * 512 + lane * 8;
    *(half8*)(KF + off) = o;
  } else if (bid < 3072) {
    // ---- V fragment tiler (transpose): 8 blocks per (b,kt) image ----
    int b3 = bid - 2048;
    int img = b3 >> 3;                     // 0..127
    int bb = img >> 6, kt = img & 63;
    int tix = ((b3 & 7) << 8) | tid;       // 0..2047
    int kq = tix >> 8;                     // 0..7
    int k2 = kq >> 2, g4 = kq & 3;
    int d0 = (tix & 255) << 2;             // 0..1020
    const float* src = v + ((size_t)(bb * SEQ + kt * 32 + k2 * 16 + g4 * 4)) * DM + d0;
    f32x4 m0 = *(const f32x4*)(src);
    f32x4 m1 = *(const f32x4*)(src + DM);
    f32x4 m2 = *(const f32x4*)(src + 2 * DM);
    f32x4 m3 = *(const f32x4*)(src + 3 * DM);
#pragma unroll
    for (int i = 0; i < 4; ++i) {
      int d = d0 + i;
      int l16 = d & 15, dt = (d >> 4) & 3, dtp = dt >> 1, w = dt & 1, h = d >> 6;
      int lane = g4 * 16 + l16;
      half4 o = {(_Float16)m0[i], (_Float16)m1[i], (_Float16)m2[i], (_Float16)m3[i]};
      size_t off = ((size_t)((bb * 16 + h) * 64 + kt)) * 2048 + (k2 * 2 + dtp) * 512 + lane * 8 + w * 4;
      *(half4*)(VF + off) = o;
    }
  } else {
    // ---- packed bucket byte tiler: 32 blocks per (b,qblk) job ----
    int b4 = bid - 3072;                   // 0..4095
    int job = b4 >> 5;                     // 0..127 = b*64+qblk
    int bb = job >> 6, qblk = job & 63;
    int tix = ((b4 & 31) << 8) | tid;      // 0..8191
    int kt = tix >> 7;
    int rem = tix & 127;
    int g4 = rem & 3, l16 = (rem >> 2) & 15, qs = rem >> 6;
    int lane = g4 * 16 + l16;
    int qrow = qblk * 32 + qs * 16 + l16;
    size_t rowbase = ((size_t)(bb * SEQ + qrow)) * SEQ;
    u32x2 wds;
#pragma unroll
    for (int k2 = 0; k2 < 2; ++k2) {
      int kk = kt * 32 + k2 * 16 + g4 * 4;
      i32x4 dv = *(const i32x4*)(diff + rowbase + kk);
      i32x4 mv = *(const i32x4*)(mask + rowbase + kk);
      u32 wd = 0;
#pragma unroll
      for (int r = 0; r < 4; ++r) {
        u32 byte = mv[r] ? ((u32)dv[r] << 2) : 80u;  // pre-shifted bucket*4; 80 = masked sentinel lane 20
        wd |= byte << (8 * r);
      }
      wds[k2] = wd;
    }
    // both qs words adjacent -> main does one b128 per iter
    size_t off = ((size_t)job) * 65536 + (size_t)kt * 1024 + (size_t)lane * 16 + (size_t)qs * 8;
    *(u32x2*)(PB + off) = wds;
  }
}

// packed-f16 silu on 4 S-values with bias gather from lanes
__device__ __forceinline__ half4 silu4(const f32x4& s, u32 u, int rbi) {
  float b0 = __int_as_float(__builtin_amdgcn_ds_bpermute((int)(u & 0xffu), rbi));
  float b1 = __int_as_float(__builtin_amdgcn_ds_bpermute((int)((u >> 8) & 0xffu), rbi));
  float b2 = __int_as_float(__builtin_amdgcn_ds_bpermute((int)((u >> 16) & 0xffu), rbi));
  float b3 = __int_as_float(__builtin_amdgcn_ds_bpermute((int)(u >> 24), rbi));
  h2v x01 = __builtin_bit_cast(h2v, __builtin_amdgcn_cvt_pkrtz(s[0], s[1])) +
            __builtin_bit_cast(h2v, __builtin_amdgcn_cvt_pkrtz(b0, b1));
  h2v x23 = __builtin_bit_cast(h2v, __builtin_amdgcn_cvt_pkrtz(s[2], s[3])) +
            __builtin_bit_cast(h2v, __builtin_amdgcn_cvt_pkrtz(b2, b3));
  const h2v NL2E = {(_Float16)-1.44269504f, (_Float16)-1.44269504f};
  const h2v ONE = {(_Float16)1.0f, (_Float16)1.0f};
  h2v m01 = x01 * NL2E, m23 = x23 * NL2E;
  h2v e01 = __builtin_bit_cast(h2v, h2exp2(__builtin_bit_cast(__half2, m01)));
  h2v e23 = __builtin_bit_cast(h2v, h2exp2(__builtin_bit_cast(__half2, m23)));
  h2v d01 = e01 + ONE, d23 = e23 + ONE;
  h2v y01 = x01 * __builtin_bit_cast(h2v, h2rcp(__builtin_bit_cast(__half2, d01)));
  h2v y23 = x23 * __builtin_bit_cast(h2v, h2rcp(__builtin_bit_cast(__half2, d23)));
  return (half4){y01[0], y01[1], y23[0], y23[1]};
}

// =================== main: barrier-free per-wave streaming ===================
// 1024 blocks x 256 thr (4 waves). Block = (b,ksp,qgrp,h): 4 waves = 4 adjacent qblks of
// the SAME head -> identical kf/vv addresses across waves (L1 reuse). XCD-bijective swizzle
// co-locates the 16 h-blocks sharing one PB region.
__global__ __launch_bounds__(256, 4) void pa_main(
    const _Float16* __restrict__ KF, const _Float16* __restrict__ VF,
    const unsigned char* __restrict__ PB, const float* __restrict__ q,
    const float* __restrict__ relbias, float* __restrict__ out) {
  const int tid = threadIdx.x, lane = tid & 63, wid = tid >> 6;
  const int l16 = lane & 15, g4 = lane >> 4;
  const int L = (blockIdx.x & 7) * 128 + (blockIdx.x >> 3);   // bijective, 8 XCDs x 128
  const int h = L & 15;
  const int qgrp = (L >> 4) & 15;
  const int ksp = (L >> 8) & 1;
  const int b = L >> 9;
  const int qblk = qgrp * 4 + wid;
  const int qbase = qblk * 32;

  // rel_bias for this head lives in lanes 0..20 (lane 20 = masked sentinel)
  const float rbv = (lane < NB) ? relbias[lane * NH + h] : -30000.0f;
  const int rbi = __float_as_int(rbv);

  // Q fragments, pre-scaled by 1/8 (B-operand: col q=l16, k=d=g4*8+j)
  half8 qf[2][2];
#pragma unroll
  for (int qs = 0; qs < 2; ++qs)
#pragma unroll
    for (int dh = 0; dh < 2; ++dh) {
      const float* s = q + ((size_t)(b * SEQ + qbase + qs * 16 + l16)) * DM + h * 64 + dh * 32 + g4 * 8;
      f32x4 a = *(const f32x4*)s;
      f32x4 c = *(const f32x4*)(s + 4);
      qf[qs][dh] = {(_Float16)(a[0] * 0.125f), (_Float16)(a[1] * 0.125f),
                    (_Float16)(a[2] * 0.125f), (_Float16)(a[3] * 0.125f),
                    (_Float16)(c[0] * 0.125f), (_Float16)(c[1] * 0.125f),
                    (_Float16)(c[2] * 0.125f), (_Float16)(c[3] * 0.125f)};
    }

  const f32x4 zf = {0.f, 0.f, 0.f, 0.f};
  f32x4 acc[2][4];
#pragma unroll
  for (int qs = 0; qs < 2; ++qs)
#pragma unroll
    for (int dt = 0; dt < 4; ++dt) acc[qs][dt] = zf;

  const _Float16* kfb = KF + ((size_t)((b * 16 + h) * 64 + ksp * 32)) * 2048 + lane * 8;
  const _Float16* vfb = VF + ((size_t)((b * 16 + h) * 64 + ksp * 32)) * 2048 + lane * 8;
  const unsigned char* pbb = PB + ((size_t)(b * 64 + qblk)) * 65536 + (size_t)(ksp * 32) * 1024 + lane * 16;

#pragma unroll 2
  for (int t = 0; t < 32; ++t) {
    half8 kfr[4], vvr[4];
#pragma unroll
    for (int j = 0; j < 4; ++j) {
      kfr[j] = *(const half8*)(kfb + (size_t)t * 2048 + j * 512);
      vvr[j] = *(const half8*)(vfb + (size_t)t * 2048 + j * 512);
    }
    i32x4 pq = *(const i32x4*)(pbb + (size_t)t * 1024);

#pragma unroll
    for (int k2 = 0; k2 < 2; ++k2) {
      // S^T = K * Q^T  (D: q=l16, kk=g4*4+r == PV A-frag layout, zero-shuffle)
      f32x4 sa[2];
#pragma unroll
      for (int qs = 0; qs < 2; ++qs) {
        sa[qs] = __builtin_amdgcn_mfma_f32_16x16x32_f16(kfr[k2 * 2 + 0], qf[qs][0], zf, 0, 0, 0);
        sa[qs] = __builtin_amdgcn_mfma_f32_16x16x32_f16(kfr[k2 * 2 + 1], qf[qs][1], sa[qs], 0, 0, 0);
      }
      half4 pf[2];
      pf[0] = silu4(sa[0], (u32)pq[k2], rbi);
      pf[1] = silu4(sa[1], (u32)pq[2 + k2], rbi);

      half4 vf0 = __builtin_shufflevector(vvr[k2 * 2 + 0], vvr[k2 * 2 + 0], 0, 1, 2, 3);
      half4 vf1 = __builtin_shufflevector(vvr[k2 * 2 + 0], vvr[k2 * 2 + 0], 4, 5, 6, 7);
      half4 vf2 = __builtin_shufflevector(vvr[k2 * 2 + 1], vvr[k2 * 2 + 1], 0, 1, 2, 3);
      half4 vf3 = __builtin_shufflevector(vvr[k2 * 2 + 1], vvr[k2 * 2 + 1], 4, 5, 6, 7);
#pragma unroll
      for (int qs = 0; qs < 2; ++qs) {
        acc[qs][0] = __builtin_amdgcn_mfma_f32_16x16x16f16(pf[qs], vf0, acc[qs][0], 0, 0, 0);
        acc[qs][1] = __builtin_amdgcn_mfma_f32_16x16x16f16(pf[qs], vf1, acc[qs][1], 0, 0, 0);
        acc[qs][2] = __builtin_amdgcn_mfma_f32_16x16x16f16(pf[qs], vf2, acc[qs][2], 0, 0, 0);
        acc[qs][3] = __builtin_amdgcn_mfma_f32_16x16x16f16(pf[qs], vf3, acc[qs][3], 0, 0, 0);
      }
    }
  }

  // epilogue: ksplit=2 partials -> atomicAdd into zeroed out
#pragma unroll
  for (int qs = 0; qs < 2; ++qs)
#pragma unroll
    for (int dt = 0; dt < 4; ++dt)
#pragma unroll
      for (int r = 0; r < 4; ++r) {
        int qrow = qbase + qs * 16 + g4 * 4 + r;
        int d = h * 64 + dt * 16 + l16;
        atomicAdd(&out[((size_t)(b * SEQ) + qrow) * DM + d], acc[qs][dt][r]);
      }
}

extern "C" void kernel_launch(void* const* d_in, const int* in_sizes, int n_in,
                              void* d_out, int out_size, void* d_ws, size_t ws_size,
                              hipStream_t stream) {
  const float* v = (const float*)d_in[0];
  const float* k = (const float*)d_in[1];
  const float* q = (const float*)d_in[2];
  const int* mask = (const int*)d_in[3];
  const int* diff = (const int*)d_in[4];
  const float* relbias = (const float*)d_in[5];
  float* out = (float*)d_out;

  _Float16* KF = (_Float16*)d_ws;
  _Float16* VF = KF + KF_HALVES;
  unsigned char* PB = (unsigned char*)(VF + VF_HALVES);
  if (ws_size < (size_t)25165824) return;

  (void)hipMemsetAsync(d_out, 0, (size_t)out_size * sizeof(float), stream);
  pa_prep<<<7168, 256, 0, stream>>>(v, k, diff, mask, KF, VF, PB);
  pa_main<<<1024, 256, 0, stream>>>(KF, VF, PB, q, relbias, out);
}